// Round 4
// baseline (510.687 us; speedup 1.0000x reference)
//
#include <hip/hip_runtime.h>
#include <math.h>

#define BB 64
#define HH 512
#define VV 50000
#define LL 400
#define MM 128
#define DD 64
#define HC 260
#define EPSF 1e-8f

typedef __attribute__((ext_vector_type(8))) short bf16x8;
typedef __attribute__((ext_vector_type(4))) float f32x4;

__device__ __forceinline__ float sigmoidf(float x){ return 1.0f/(1.0f+expf(-x)); }
__device__ __forceinline__ unsigned short bf16_rne(float f){
  unsigned u = __float_as_uint(f);
  return (unsigned short)((u + 0x7fffu + ((u >> 16) & 1u)) >> 16);
}
__device__ __forceinline__ float wave_max(float v){
  #pragma unroll
  for(int o=32;o;o>>=1) v = fmaxf(v, __shfl_xor(v,o));
  return v;
}
__device__ __forceinline__ float wave_sum(float v){
  #pragma unroll
  for(int o=32;o;o>>=1) v += __shfl_xor(v,o);
  return v;
}

// ---------------- embed + concat builders ----------------
__global__ void k_embed(const int* __restrict__ ids, const float* __restrict__ emb,
                        const float* __restrict__ h0, float* __restrict__ xcat1,
                        float* __restrict__ xcat2){
  int idx = blockIdx.x*256 + threadIdx.x;           // 64*512
  if (idx >= BB*HH) return;
  int b = idx >> 9, h = idx & 511;
  float e = emb[(long)ids[b]*HH + h];
  xcat1[b*1024 + h] = e;
  xcat2[b*1024 + h] = e;
  xcat1[b*1024 + 512 + h] = h0[idx];
}

// ---------------- wave-per-output GEMV: C[b,n] = (A[+A2])[b,:] . W[n,:] ----------------
template<int NB, int FUSE>
__global__ __launch_bounds__(256) void k_gemv(const float* __restrict__ A,
                                              const float* __restrict__ A2,
                                              const float* __restrict__ W,
                                              const float* __restrict__ b1,
                                              float* __restrict__ C,
                                              int K, int N, int ldc){
  int b = blockIdx.y;
  int wid = threadIdx.x >> 6, lane = threadIdx.x & 63;
  int n = blockIdx.x*4 + wid;
  if (n >= N) return;
  const float4* A4  = (const float4*)(A + (long)b*K);
  const float4* A24 = (const float4*)(A2 + (long)b*K);
  const float4* W4  = (const float4*)(W + (long)n*K);
  int K4 = K >> 2;
  float acc = 0.f;
  for (int k = lane; k < K4; k += 64){
    float4 a = A4[k];
    if (FUSE){ float4 a2 = A24[k]; a.x+=a2.x; a.y+=a2.y; a.z+=a2.z; a.w+=a2.w; }
    float4 w = W4[k];
    acc += a.x*w.x + a.y*w.y + a.z*w.z + a.w*w.w;
  }
  acc = wave_sum(acc);
  if (lane == 0){
    if (NB) acc += b1[n];
    C[(long)b*ldc + n] = acc;
  }
}

// ---------------- aw = softmax(tc+ia+ts) over L ; also ncov = cov + ia ----------------
__global__ __launch_bounds__(256) void k_softmax_aw(const float* __restrict__ ia,
                                                    const float* __restrict__ ts,
                                                    const float* __restrict__ tc,
                                                    const float* __restrict__ cov,
                                                    float* __restrict__ aw,
                                                    float* __restrict__ ncov){
  int b = blockIdx.x, t = threadIdx.x;
  int i0 = t, i1 = t + 256;
  float ia0 = ia[b*LL+i0];
  float x0 = ia0 + ts[b*LL+i0] + tc[b*LL+i0];
  float ia1 = (i1 < LL) ? ia[b*LL+i1] : 0.f;
  float x1 = (i1 < LL) ? (ia1 + ts[b*LL+i1] + tc[b*LL+i1]) : -INFINITY;
  ncov[b*LL + i0] = cov[b*LL + i0] + ia0;
  if (i1 < LL) ncov[b*LL + i1] = cov[b*LL + i1] + ia1;
  __shared__ float sm[4], ss[4];
  float m = wave_max(fmaxf(x0, x1));
  if ((t & 63) == 0) sm[t>>6] = m;
  __syncthreads();
  m = fmaxf(fmaxf(sm[0], sm[1]), fmaxf(sm[2], sm[3]));
  float e0 = expf(x0 - m);
  float e1 = (i1 < LL) ? expf(x1 - m) : 0.0f;
  float s = wave_sum(e0 + e1);
  if ((t & 63) == 0) ss[t>>6] = s;
  __syncthreads();
  float tot = ss[0] + ss[1] + ss[2] + ss[3];
  float inv = 1.0f / tot;
  aw[b*LL + i0] = e0 * inv;
  if (i1 < LL) aw[b*LL + i1] = e1 * inv;
}

// ---------------- attn_applied partials: grid (64 b, 16 l-chunks of 25) ----------------
__global__ __launch_bounds__(256) void k_attn_part(const float* __restrict__ aw,
                                                   const float* __restrict__ enc,
                                                   float* __restrict__ part){
  int b = blockIdx.x, lc = blockIdx.y, t = threadIdx.x;
  const float* awb = aw + b*LL + lc*25;
  const float* eb  = enc + ((long)b*LL + lc*25)*HH;
  float a0 = 0.f, a1 = 0.f;
  for (int l = 0; l < 25; l++){
    float a = awb[l];
    a0 += a * eb[(long)l*HH + t];
    a1 += a * eb[(long)l*HH + t + 256];
  }
  part[((b*16 + lc) << 9) + t]       = a0;
  part[((b*16 + lc) << 9) + t + 256] = a1;
}

__global__ void k_attn_reduce(const float* __restrict__ part, float* __restrict__ xcat2){
  int idx = blockIdx.x*256 + threadIdx.x;       // 64*512
  if (idx >= BB*HH) return;
  int b = idx >> 9, h = idx & 511;
  float s = 0.f;
  #pragma unroll
  for (int lc = 0; lc < 16; lc++) s += part[((b*16 + lc) << 9) + h];
  xcat2[b*1024 + 512 + h] = s;
}

// ---------------- pre GEMV, K-split: grid (16 n-quads, 64 b, which*8+chunk) ----------------
__global__ __launch_bounds__(256) void k_pre_gemv(const float* __restrict__ h0,
                                                  const float* __restrict__ mem,
                                                  const float* __restrict__ rW,
                                                  const float* __restrict__ wW,
                                                  float* __restrict__ part){
  int wid = threadIdx.x >> 6, lane = threadIdx.x & 63;
  int n = blockIdx.x*4 + wid;        // 0..63
  int b = blockIdx.y;
  int z = blockIdx.z;                // which*8 + chunk
  int which = z >> 3, chunk = z & 7;
  const float* W = which ? wW : rW;
  const float4* W4 = (const float4*)(W + (long)n*8704 + chunk*1088);
  const float4* H4 = (const float4*)(h0 + (long)b*HH);
  const float4* M4 = (const float4*)(mem + (long)b*8192 + (chunk*1088 - 512));
  float acc = 0.f;
  #pragma unroll
  for (int i = 0; i < 5; i++){
    int k4 = lane + i*64;            // float4 index within chunk (272 total)
    if (k4 < 272){
      int kg4 = chunk*272 + k4;      // global float4 index
      float4 a = (kg4 < 128) ? H4[kg4] : M4[k4];
      float4 w = W4[k4];
      acc += a.x*w.x + a.y*w.y + a.z*w.z + a.w*w.w;
    }
  }
  acc = wave_sum(acc);
  if (lane == 0) part[z*4096 + b*64 + n] = acc;
}

__global__ void k_pre_reduce(const float* __restrict__ part, const float* __restrict__ rb,
                             const float* __restrict__ wb, float* __restrict__ pre_r,
                             float* __restrict__ pre_w){
  int idx = blockIdx.x*256 + threadIdx.x;     // 8192
  if (idx >= 8192) return;
  int which = idx >> 12;
  int r = idx & 4095;
  float s = 0.f;
  #pragma unroll
  for (int c = 0; c < 8; c++) s += part[((which<<3)+c)*4096 + r];
  int n = r & 63;
  s += which ? wb[n] : rb[n];
  (which ? pre_w : pre_r)[r] = s;
}

// ---------------- gates GEMV for r/w heads: wave per n, loop b-octet ----------------
// grid (260 n-quads, 8 b-octets, 2 which). W rows live in registers across 8 b's.
__global__ __launch_bounds__(256) void k_gates_rw(const float* __restrict__ pre_r,
    const float* __restrict__ pre_w, const float* __restrict__ read_h,
    const float* __restrict__ write_h,
    const float* __restrict__ rWih, const float* __restrict__ rWhh,
    const float* __restrict__ rbih, const float* __restrict__ rbhh,
    const float* __restrict__ wWih, const float* __restrict__ wWhh,
    const float* __restrict__ wbih, const float* __restrict__ wbhh,
    float* __restrict__ g_r, float* __restrict__ g_w){
  int which = blockIdx.z;
  int bo = blockIdx.y;
  int wid = threadIdx.x >> 6, lane = threadIdx.x & 63;
  int n = blockIdx.x*4 + wid;     // < 1040
  const float* pre = which ? pre_w : pre_r;     // (64,64)
  const float* hh  = which ? write_h : read_h;  // (64,260)
  const float* Wih = which ? wWih : rWih;       // (1040,64)
  const float* Whh = which ? wWhh : rWhh;       // (1040,260)
  float* gout = which ? g_w : g_r;
  float wih_l = Wih[(long)n*64 + lane];
  const float* wr = Whh + (long)n*HC;
  float whh_l[5];
  #pragma unroll
  for (int i = 0; i < 5; i++){
    int k = lane + i*64;
    whh_l[i] = (k < HC) ? wr[k] : 0.f;
  }
  float bsum = (which ? wbih : rbih)[n] + (which ? wbhh : rbhh)[n];
  #pragma unroll
  for (int i = 0; i < 8; i++){
    int b = bo*8 + i;
    float acc = pre[b*64 + lane] * wih_l;
    const float* hb = hh + (long)b*HC;
    #pragma unroll
    for (int j = 0; j < 5; j++){
      int k = lane + j*64;
      if (k < HC) acc += whh_l[j]*hb[k];
    }
    acc = wave_sum(acc);
    if (lane == 0) gout[(long)b*4*HC + n] = acc + bsum;
  }
}

// ---------------- fused r+w LSTM elementwise ----------------
__global__ void k_lstm_rw(const float* __restrict__ g_r, const float* __restrict__ g_w,
                          const float* __restrict__ read_c, const float* __restrict__ write_c,
                          float* __restrict__ rh, float* __restrict__ wh){
  int idx = blockIdx.x*256 + threadIdx.x;    // 2*64*260 = 33280
  if (idx >= 2*BB*HC) return;
  int which = idx >= BB*HC;
  int r = which ? idx - BB*HC : idx;
  int b = r / HC, j = r - b*HC;
  const float* g = (which ? g_w : g_r) + (long)b*4*HC;
  float c2 = sigmoidf(g[HC + j]) * (which ? write_c : read_c)[r]
           + sigmoidf(g[j]) * tanhf(g[2*HC + j]);
  (which ? wh : rh)[r] = sigmoidf(g[3*HC + j]) * tanhf(c2);
}

// ---------------- addressing fused with read_in / new_memory: grid (64, 2) -------------
__global__ __launch_bounds__(128) void k_address(const float* __restrict__ rh,
                                                 const float* __restrict__ whv,
                                                 const float* __restrict__ rheads,
                                                 const float* __restrict__ wheads,
                                                 const float* __restrict__ mem,
                                                 float* __restrict__ xcat3,
                                                 float* __restrict__ nmem){
  int which = blockIdx.y;
  int b = blockIdx.x, m = threadIdx.x;
  const float* hc = which ? whv : rh;
  const float* heads0 = which ? wheads : rheads;
  const float* mr = mem + ((long)b*MM + m)*DD;
  float s = 0.f, q = 0.f;
  #pragma unroll 8
  for (int d = 0; d < DD; d++){ float v = mr[d]; s += v; q += v*v; }
  float key  = hc[b*HC + m];
  float kstr = expf(hc[b*HC + 64]);
  float gate = sigmoidf(hc[b*HC + 65]);
  float nk = fmaxf(fabsf(key)*8.0f, EPSF);
  float nm = fmaxf(sqrtf(q), EPSF);
  float z  = kstr * (key*s) / (nk*nm);
  __shared__ float sm[2], ss[2];
  __shared__ float sw[128];
  float mx = wave_max(z);
  if ((m & 63) == 0) sm[m>>6] = mx;
  __syncthreads();
  mx = fmaxf(sm[0], sm[1]);
  float e = expf(z - mx);
  float wsum = wave_sum(e);
  if ((m & 63) == 0) ss[m>>6] = wsum;
  __syncthreads();
  float content = e / (ss[0] + ss[1]);
  float w = gate*content + (1.0f - gate)*heads0[m];   // heads[0]: batch-0 row broadcast
  if (which == 0){
    // read path: read_in[b,d] = sum_m w[m]*mem[b,m,d]
    sw[m] = w;
    __syncthreads();
    if (m < 64){
      float acc = 0.f;
      const float* mb = mem + (long)b*MM*DD + m;
      #pragma unroll 8
      for (int mm = 0; mm < MM; mm++) acc += sw[mm]*mb[(long)mm*DD];
      xcat3[b*576 + 512 + m] = acc;
    }
  } else {
    // write path: new_memory row m
    float we = sigmoidf(hc[b*HC + 68 + m]);
    float wa = sigmoidf(hc[b*HC + 132 + m]);
    float scale = 1.0f - w*we;
    float addv  = w*wa;
    const float4* mr4 = (const float4*)mr;
    float4* out4 = (float4*)(nmem + ((long)b*MM + m)*DD);
    #pragma unroll
    for (int d4 = 0; d4 < 16; d4++){
      float4 v = mr4[d4];
      v.x = v.x*scale + addv; v.y = v.y*scale + addv;
      v.z = v.z*scale + addv; v.w = v.w*scale + addv;
      out4[d4] = v;
    }
  }
}

// ---------------- main LSTM fused: wave per (b,j) computes 4 gate dots + elementwise ----
__global__ __launch_bounds__(256) void k_lstm_main(const float* __restrict__ xcat3,
                                                   const float* __restrict__ h0,
                                                   const float* __restrict__ lWih,
                                                   const float* __restrict__ lWhh,
                                                   const float* __restrict__ bih,
                                                   const float* __restrict__ bhh,
                                                   const float* __restrict__ c0,
                                                   float* __restrict__ h1,
                                                   float* __restrict__ c1,
                                                   unsigned short* __restrict__ c1b){
  int wid = threadIdx.x >> 6, lane = threadIdx.x & 63;
  int j = blockIdx.x*4 + wid;        // 0..511
  int b = blockIdx.y;
  const float4* A1 = (const float4*)(xcat3 + (long)b*576);   // 144 f4
  const float4* A2 = (const float4*)(h0 + (long)b*HH);       // 128 f4
  float gv[4];
  #pragma unroll
  for (int g = 0; g < 4; g++){
    int n = g*HH + j;
    const float4* W1 = (const float4*)(lWih + (long)n*576);
    const float4* W2 = (const float4*)(lWhh + (long)n*HH);
    float s = 0.f;
    #pragma unroll
    for (int i = 0; i < 3; i++){
      int k = lane + i*64;
      if (k < 144){ float4 a = A1[k], w = W1[k]; s += a.x*w.x + a.y*w.y + a.z*w.z + a.w*w.w; }
    }
    #pragma unroll
    for (int i = 0; i < 2; i++){
      int k = lane + i*64;
      float4 a = A2[k], w = W2[k]; s += a.x*w.x + a.y*w.y + a.z*w.z + a.w*w.w;
    }
    gv[g] = wave_sum(s);
  }
  if (lane == 0){
    #pragma unroll
    for (int g = 0; g < 4; g++){ int n = g*HH + j; gv[g] += bih[n] + bhh[n]; }
    float c2 = sigmoidf(gv[1])*c0[b*HH + j] + sigmoidf(gv[0])*tanhf(gv[2]);
    h1[b*HH + j] = sigmoidf(gv[3])*tanhf(c2);
    c1[b*HH + j] = c2;
    c1b[b*HH + j] = bf16_rne(c2);
  }
}

// ---------------- logits: bf16 MFMA, no LDS, depth-2 software pipeline ----------------
// C(64,50000) = c1b(64,512,bf16) @ out_W^T(fp32->bf16 on the fly) + bias
__global__ __launch_bounds__(256) void k_logits_mfma(const unsigned short* __restrict__ Ab,
                                                     const float* __restrict__ W,
                                                     const float* __restrict__ bias,
                                                     float* __restrict__ C){
  int wid = threadIdx.x >> 6, lane = threadIdx.x & 63;
  int strip = blockIdx.x*4 + wid;          // 3125 strips of 16 n
  if (strip >= 3125) return;
  int nl = lane & 15;                      // n offset within strip / m offset in frags
  int q  = lane >> 4;                      // quad -> k = q*8 + j
  int n  = strip*16 + nl;
  const float4* wp  = (const float4*)(W + (long)n*HH + q*8);     // +8 f4 per ks
  const bf16x8* a0p = (const bf16x8*)(Ab + (long)nl*HH + q*8);   // +4 per ks
  const bf16x8* a1p = (const bf16x8*)(Ab + (long)(16+nl)*HH + q*8);
  const bf16x8* a2p = (const bf16x8*)(Ab + (long)(32+nl)*HH + q*8);
  const bf16x8* a3p = (const bf16x8*)(Ab + (long)(48+nl)*HH + q*8);
  f32x4 acc0 = {0.f,0.f,0.f,0.f}, acc1 = acc0, acc2 = acc0, acc3 = acc0;
  float4 wA[3], wB[3];
  bf16x8 fa0[3], fa1[3], fa2[3], fa3[3];
  #pragma unroll
  for (int p = 0; p < 2; p++){
    wA[p] = wp[p*8]; wB[p] = wp[p*8 + 1];
    fa0[p] = a0p[p*4]; fa1[p] = a1p[p*4];
    fa2[p] = a2p[p*4]; fa3[p] = a3p[p*4];
  }
  #pragma unroll
  for (int ks = 0; ks < 16; ks++){
    int cur = ks % 3;
    if (ks < 14){
      int nx = (ks + 2) % 3;
      wA[nx] = wp[(ks+2)*8]; wB[nx] = wp[(ks+2)*8 + 1];
      fa0[nx] = a0p[(ks+2)*4]; fa1[nx] = a1p[(ks+2)*4];
      fa2[nx] = a2p[(ks+2)*4]; fa3[nx] = a3p[(ks+2)*4];
    }
    bf16x8 bf;
    bf[0] = (short)bf16_rne(wA[cur].x); bf[1] = (short)bf16_rne(wA[cur].y);
    bf[2] = (short)bf16_rne(wA[cur].z); bf[3] = (short)bf16_rne(wA[cur].w);
    bf[4] = (short)bf16_rne(wB[cur].x); bf[5] = (short)bf16_rne(wB[cur].y);
    bf[6] = (short)bf16_rne(wB[cur].z); bf[7] = (short)bf16_rne(wB[cur].w);
    acc0 = __builtin_amdgcn_mfma_f32_16x16x32_bf16(fa0[cur], bf, acc0, 0, 0, 0);
    acc1 = __builtin_amdgcn_mfma_f32_16x16x32_bf16(fa1[cur], bf, acc1, 0, 0, 0);
    acc2 = __builtin_amdgcn_mfma_f32_16x16x32_bf16(fa2[cur], bf, acc2, 0, 0, 0);
    acc3 = __builtin_amdgcn_mfma_f32_16x16x32_bf16(fa3[cur], bf, acc3, 0, 0, 0);
  }
  float bv = bias[n];
  #pragma unroll
  for (int r = 0; r < 4; r++){
    int m = q*4 + r;
    C[(long)(m     )*VV + n] = acc0[r] + bv;
    C[(long)(m + 16)*VV + n] = acc1[r] + bv;
    C[(long)(m + 32)*VV + n] = acc2[r] + bv;
    C[(long)(m + 48)*VV + n] = acc3[r] + bv;
  }
}

// ---------------- log_softmax: partials then fused lse+subtract ----------------
__global__ __launch_bounds__(256) void k_ls1(const float* __restrict__ lp,
                                             float* __restrict__ pm, float* __restrict__ ps){
  int b = blockIdx.y, c = blockIdx.x, t = threadIdx.x;   // grid (25, 64)
  const float* row = lp + (long)b*VV + c*2000;
  float mx = -INFINITY;
  for (int i = t; i < 2000; i += 256) mx = fmaxf(mx, row[i]);
  __shared__ float sm[4], ss[4];
  mx = wave_max(mx);
  if ((t & 63) == 0) sm[t>>6] = mx;
  __syncthreads();
  mx = fmaxf(fmaxf(sm[0], sm[1]), fmaxf(sm[2], sm[3]));
  float s = 0.f;
  for (int i = t; i < 2000; i += 256) s += expf(row[i] - mx);
  s = wave_sum(s);
  if ((t & 63) == 0) ss[t>>6] = s;
  __syncthreads();
  if (t == 0){ pm[b*25 + c] = mx; ps[b*25 + c] = ss[0]+ss[1]+ss[2]+ss[3]; }
}

__global__ __launch_bounds__(256) void k_ls3(float* __restrict__ lp,
                                             const float* __restrict__ pm,
                                             const float* __restrict__ ps){
  int b = blockIdx.y, c = blockIdx.x, t = threadIdx.x;   // grid (196, 64)
  float m = -INFINITY;
  #pragma unroll
  for (int k = 0; k < 25; k++) m = fmaxf(m, pm[b*25 + k]);
  float s = 0.f;
  #pragma unroll
  for (int k = 0; k < 25; k++) s += ps[b*25 + k]*expf(pm[b*25 + k] - m);
  float lse = m + logf(s);
  int i = c*256 + t;
  if (i < VV) lp[(long)b*VV + i] -= lse;
}

extern "C" void kernel_launch(void* const* d_in, const int* in_sizes, int n_in,
                              void* d_out, int out_size, void* d_ws, size_t ws_size,
                              hipStream_t stream) {
  const int*   ids     = (const int*)  d_in[0];
  const float* h0      = (const float*)d_in[1];
  const float* c0      = (const float*)d_in[2];
  const float* enc     = (const float*)d_in[3];
  const float* cov     = (const float*)d_in[5];
  const float* mem     = (const float*)d_in[6];
  const float* rheads  = (const float*)d_in[7];
  const float* wheads  = (const float*)d_in[8];
  const float* read_h  = (const float*)d_in[9];
  const float* read_c  = (const float*)d_in[10];
  const float* write_h = (const float*)d_in[11];
  const float* write_c = (const float*)d_in[12];
  const float* emb     = (const float*)d_in[13];
  const float* attn_W  = (const float*)d_in[14];
  const float* attn_b  = (const float*)d_in[15];
  const float* cov_W   = (const float*)d_in[16];
  const float* state_W = (const float*)d_in[17];
  const float* comb_W  = (const float*)d_in[18];
  const float* comb_b  = (const float*)d_in[19];
  const float* rpre_W  = (const float*)d_in[20];
  const float* rpre_b  = (const float*)d_in[21];
  const float* wpre_W  = (const float*)d_in[22];
  const float* wpre_b  = (const float*)d_in[23];
  const float* r_Wih   = (const float*)d_in[24];
  const float* r_Whh   = (const float*)d_in[25];
  const float* r_bih   = (const float*)d_in[26];
  const float* r_bhh   = (const float*)d_in[27];
  const float* w_Wih   = (const float*)d_in[28];
  const float* w_Whh   = (const float*)d_in[29];
  const float* w_bih   = (const float*)d_in[30];
  const float* w_bhh   = (const float*)d_in[31];
  const float* l_Wih   = (const float*)d_in[32];
  const float* l_Whh   = (const float*)d_in[33];
  const float* l_bih   = (const float*)d_in[34];
  const float* l_bhh   = (const float*)d_in[35];
  const float* out_W   = (const float*)d_in[36];
  const float* out_b   = (const float*)d_in[37];

  float* out  = (float*)d_out;
  float* lp   = out;                 // (64, 50000)
  float* h1   = out + 3200000;       // (64, 512)
  float* c1   = h1 + 32768;          // (64, 512)
  float* nmem = c1 + 32768;          // (64, 128, 64)
  float* ncov = nmem + 524288;       // (64, 400)

  float* w = (float*)d_ws;
  float* xcat1 = w;                  // 65536   [embedded | h0]
  float* xcat2 = xcat1 + 65536;      // 65536   [embedded | attn_applied]
  float* xcat3 = xcat2 + 65536;      // 36864   [out0 | read_in]
  float* ia    = xcat3 + 36864;      // 25600
  float* ts    = ia + 25600;         // 25600
  float* tc    = ts + 25600;         // 25600
  float* aw    = tc + 25600;         // 25600
  float* U     = aw + 25600;         // 557056  shared: attn partials / pre partials
  float* pre_r = U + 557056;         // 4096
  float* pre_w = pre_r + 4096;       // 4096
  float* g_r   = pre_w + 4096;       // 66560
  float* g_w   = g_r + 66560;        // 66560
  float* rh    = g_w + 66560;        // 16640
  float* wh    = rh + 16640;         // 16640
  float* pm    = wh + 16640;         // 1600
  float* ps    = pm + 1600;          // 1600
  unsigned short* c1b = (unsigned short*)(ps + 1600);   // 32768 bf16

  // attention path
  k_embed<<<128, 256, 0, stream>>>(ids, emb, h0, xcat1, xcat2);
  k_gemv<1,0><<<dim3(100,64), 256, 0, stream>>>(xcat1, xcat1, attn_W, attn_b, ia, 1024, LL, LL);
  k_gemv<0,0><<<dim3(100,64), 256, 0, stream>>>(c0, c0, state_W, nullptr, ts, HH, LL, LL);
  k_gemv<0,1><<<dim3(100,64), 256, 0, stream>>>(cov, ia, cov_W, nullptr, tc, LL, LL, LL);
  k_softmax_aw<<<64, 256, 0, stream>>>(ia, ts, tc, cov, aw, ncov);
  k_attn_part<<<dim3(64,16), 256, 0, stream>>>(aw, enc, U);
  k_attn_reduce<<<128, 256, 0, stream>>>(U, xcat2);
  k_gemv<1,0><<<dim3(128,64), 256, 0, stream>>>(xcat2, xcat2, comb_W, comb_b, xcat3, 1024, HH, 576);

  // pre-projections (K=8704, 8-way K-split GEMV)
  k_pre_gemv<<<dim3(16,64,16), 256, 0, stream>>>(h0, mem, rpre_W, wpre_W, U);
  k_pre_reduce<<<32, 256, 0, stream>>>(U, rpre_b, wpre_b, pre_r, pre_w);

  // read/write head gates + LSTMs
  k_gates_rw<<<dim3(260,8,2), 256, 0, stream>>>(pre_r, pre_w, read_h, write_h,
      r_Wih, r_Whh, r_bih, r_bhh, w_Wih, w_Whh, w_bih, w_bhh, g_r, g_w);
  k_lstm_rw<<<130, 256, 0, stream>>>(g_r, g_w, read_c, write_c, rh, wh);

  // addressing fused with read_in / new_memory
  k_address<<<dim3(64,2), 128, 0, stream>>>(rh, wh, rheads, wheads, mem, xcat3, nmem);

  // main LSTM (fused gates GEMV + elementwise, emits bf16 c1)
  k_lstm_main<<<dim3(128,64), 256, 0, stream>>>(xcat3, h0, l_Wih, l_Whh, l_bih, l_bhh,
                                                c0, h1, c1, c1b);

  // output projection (bf16 MFMA, pipelined) + log_softmax
  k_logits_mfma<<<782, 256, 0, stream>>>(c1b, out_W, out_b, lp);
  k_ls1<<<dim3(25,64), 256, 0, stream>>>(lp, pm, ps);
  k_ls3<<<dim3(196,64), 256, 0, stream>>>(lp, pm, ps);
}